// Round 1
// baseline (38.746 us; speedup 1.0000x reference)
//
#include <hip/hip_runtime.h>

#ifndef __has_builtin
#define __has_builtin(x) 0
#endif

#if __has_builtin(__builtin_amdgcn_sdot4)
#define DOT4(a, b, c) __builtin_amdgcn_sdot4((a), (b), (c), false)
#else
__device__ __forceinline__ int dot4_sw(int a, int b, int c) {
#pragma unroll
    for (int k = 0; k < 4; ++k)
        c += (int)(signed char)((a >> (8 * k)) & 0xff) *
             (int)(signed char)((b >> (8 * k)) & 0xff);
    return c;
}
#define DOT4(a, b, c) dot4_sw((a), (b), (c))
#endif

constexpr int CH   = 256;   // channels
constexpr int NPIX = 1024;  // 32*32
constexpr int TW   = 36;    // padded LDS tile dim (32 + 2*2 halo)
constexpr float BN_EPS = 1e-5f;

// One block per (n, group). 256 threads, each owns 4 consecutive pixels.
__global__ __launch_bounds__(256, 4)
void bconv_fused(const float* __restrict__ x,
                 const float* __restrict__ wgt,
                 const float* __restrict__ gamma,
                 const float* __restrict__ beta,
                 const float* __restrict__ rmean,
                 const float* __restrict__ rvar,
                 float* __restrict__ out)
{
    __shared__ __align__(16) int TP[TW * TW];  // int8x4 over the 4 group channels

    const int tid = threadIdx.x;
    const int n   = blockIdx.x >> 6;
    const int g   = blockIdx.x & 63;

    // zero the padded tile (border must be 0 == conv zero-padding)
#pragma unroll
    for (int i = 0; i < 6; ++i) {
        int idx = tid + i * 256;
        if (idx < TW * TW) TP[idx] = 0;
    }

    // pack binarized weights (wave-uniform): wq[c2][tap], one int8 lane per ci
    const float* wp = wgt + g * 144;  // group g: rows g*4..g*4+3, 36 floats each
    int wq[4][9];
#pragma unroll
    for (int c2 = 0; c2 < 4; ++c2)
#pragma unroll
        for (int t = 0; t < 9; ++t) {
            int pk = 0;
#pragma unroll
            for (int ci = 0; ci < 4; ++ci) {
                float wv = wp[c2 * 36 + ci * 9 + t];
                int s = (wv > 0.f) ? 1 : ((wv < 0.f) ? -1 : 0);
                pk |= (s & 0xff) << (8 * ci);
            }
            wq[c2][t] = pk;
        }

    // BN constants for this group's 4 input channels.
    // Mimic numpy op order exactly: inv = gamma * (1/sqrt(var+eps)); no FMA.
    float inv[4], bias[4];
#pragma unroll
    for (int ci = 0; ci < 4; ++ci) {
        const int c = g * 4 + ci;
        float r  = __fdiv_rn(1.0f, __fsqrt_rn(__fadd_rn(rvar[c], BN_EPS)));
        inv[ci]  = __fmul_rn(gamma[c], r);
        bias[ci] = __fsub_rn(beta[c], __fmul_rn(rmean[c], inv[ci]));
    }

    const int pix0 = tid * 4;
    const int row  = pix0 >> 5;
    const int col0 = pix0 & 31;

    // stage: binarize 4 pixels x 4 channels, pack over ci, write to LDS
    {
        float4 xa[4];
#pragma unroll
        for (int ci = 0; ci < 4; ++ci) {
            const float* xp = x + ((size_t)(n * CH + g * 4 + ci)) * NPIX + pix0;
            xa[ci] = *(const float4*)xp;
        }
        __syncthreads();  // zero-fill complete before interior writes
        int pk[4];
#pragma unroll
        for (int p = 0; p < 4; ++p) {
            int v = 0;
#pragma unroll
            for (int ci = 0; ci < 4; ++ci) {
                float h = __fadd_rn(__fmul_rn(((const float*)&xa[ci])[p], inv[ci]), bias[ci]);
                int s = (h > 0.f) ? 1 : ((h < 0.f) ? -1 : 0);
                v |= (s & 0xff) << (8 * ci);
            }
            pk[p] = v;
        }
        const int idx = (row + 2) * TW + (col0 + 2);
        *(int2*)&TP[idx]     = make_int2(pk[0], pk[1]);  // 8B-aligned ds_write_b64 x2
        *(int2*)&TP[idx + 2] = make_int2(pk[2], pk[3]);
    }
    __syncthreads();

    // compute: 3 rows x 8 packed ints cover all 9 dilated taps for 4 pixels
    int a[3][8];
#pragma unroll
    for (int kh = 0; kh < 3; ++kh) {
        const int base = (row + 2 * kh) * TW + col0;  // 16B aligned (col0 % 4 == 0)
        int4 lo = *(const int4*)&TP[base];
        int4 hi = *(const int4*)&TP[base + 4];
        a[kh][0] = lo.x; a[kh][1] = lo.y; a[kh][2] = lo.z; a[kh][3] = lo.w;
        a[kh][4] = hi.x; a[kh][5] = hi.y; a[kh][6] = hi.z; a[kh][7] = hi.w;
    }

#pragma unroll
    for (int c2 = 0; c2 < 4; ++c2) {
        const int co = c2 * 64 + g;  // channel shuffle: conv ch g*4+c2 -> out ch c2*64+g
        const size_t off = ((size_t)(n * CH + co)) * NPIX + pix0;
        float4 sc = *(const float4*)(x + off);  // identity shortcut
        float4 o;
#pragma unroll
        for (int p = 0; p < 4; ++p) {
            int acc = 0;
#pragma unroll
            for (int kh = 0; kh < 3; ++kh)
#pragma unroll
                for (int kw = 0; kw < 3; ++kw)
                    acc = DOT4(a[kh][p + 2 * kw], wq[c2][kh * 3 + kw], acc);
            ((float*)&o)[p] = __fadd_rn((float)acc, ((const float*)&sc)[p]);
        }
        *(float4*)(out + off) = o;
    }
}

extern "C" void kernel_launch(void* const* d_in, const int* in_sizes, int n_in,
                              void* d_out, int out_size, void* d_ws, size_t ws_size,
                              hipStream_t stream) {
    const float* x     = (const float*)d_in[0];
    const float* wgt   = (const float*)d_in[1];
    const float* gamma = (const float*)d_in[2];
    const float* beta  = (const float*)d_in[3];
    const float* rmean = (const float*)d_in[4];
    const float* rvar  = (const float*)d_in[5];
    float* out = (float*)d_out;

    const int N = in_sizes[0] / (CH * NPIX);  // 64
    dim3 grid(N * 64);
    bconv_fused<<<grid, 256, 0, stream>>>(x, wgt, gamma, beta, rmean, rvar, out);
}